// Round 3
// baseline (488.308 us; speedup 1.0000x reference)
//
#include <hip/hip_runtime.h>
#include <hip/hip_bf16.h>

// Problem constants (from reference)
constexpr int NN   = 10000;  // N_NODES
constexpr int DMAX = 128;    // D_MAX
constexpr int ROWS = 128;    // B*F = 2*64 values per node

// ---------------------------------------------------------------------------
// Kernel 1: transpose x (128, 10000) -> xT (10000, 128): each node's 128
// (b,f) values become one contiguous 512B line (coalesced neighbor gathers).
// ---------------------------------------------------------------------------
__global__ __launch_bounds__(256) void transpose_kernel(
    const float* __restrict__ x, float* __restrict__ xT)
{
    __shared__ float tile[32][33];
    const int n0 = blockIdx.x * 32;
    const int r0 = blockIdx.y * 32;
    const int tx = threadIdx.x;   // 0..31
    const int ty = threadIdx.y;   // 0..7
    #pragma unroll
    for (int i = 0; i < 32; i += 8) {
        const int r = r0 + ty + i;
        const int n = n0 + tx;
        if (n < NN) tile[ty + i][tx] = x[(size_t)r * NN + n];
    }
    __syncthreads();
    #pragma unroll
    for (int i = 0; i < 32; i += 8) {
        const int n = n0 + ty + i;
        const int r = r0 + tx;
        if (n < NN) xT[(size_t)n * ROWS + r] = tile[tx][ty + i];
    }
}

// ---------------------------------------------------------------------------
// Register-resident exact median. 4 lanes per column (q = lane>>4), each lane
// holds up to QC values in VGPRs (gathered once). Bracketed quickselect:
//   cheap passes (count only, 2 VALU/elem) narrow [lo,hi] with the pivot;
//   snap passes (count + mx=max{v<=m}, mn=min{v>m}) give exact termination:
//     c==mid+1 -> x=mx ; c==mid -> x=mn ; lo>=hi -> x=lo (duplicate-safe,
//     bracket snaps to data values so it strictly shrinks).
// Invariant: answer in (lo, hi]. The 4 lanes of a column group carry identical
// scalar state, so they become inactive together (shfl partners always live).
// ---------------------------------------------------------------------------
template<int QC>
__device__ __forceinline__ float median_sel(const float* __restrict__ xT,
                                            const int* __restrict__ idxp,
                                            int ln, int col, int q)
{
    const float INF = 1e30f;
    float data[QC];
    #pragma unroll
    for (int j = 0; j < QC; ++j) {
        const int jj = q * QC + j;
        // 16 lanes of a quarter-group share idxp[jj] (L1 broadcast); the
        // gather itself is 16 consecutive floats = one 64B segment per group.
        data[j] = (jj < ln) ? xT[(size_t)idxp[jj] * ROWS + col] : INF;
    }

    const int   mid  = (ln - 1) >> 1;
    const float invd = 1.0f / (0.4f * (float)ln);   // ~1/(pdf(0)*ln), Newton slope
    float lo = -64.f, hi = 64.f, m = 0.f, x = 0.f;  // |data| < 10 << 64
    bool active = true, need_snap = false;
    int  pass = 0;

    while (__ballot(active) != 0ull) {
        if (active) {
            const bool dosnap = need_snap || (pass >= 6);
            int   c  = 0;
            float mx = -INF, mn = INF;
            if (dosnap) {
                #pragma unroll
                for (int j = 0; j < QC; ++j) {
                    const float v  = data[j];
                    const bool  le = v <= m;
                    c  += le ? 1 : 0;
                    mx  = le ? fmaxf(mx, v) : mx;
                    mn  = le ? mn : fminf(mn, v);
                }
            } else {
                #pragma unroll
                for (int j = 0; j < QC; ++j)
                    c += (data[j] <= m) ? 1 : 0;   // INF pads never count
            }
            // combine the 4 quarter-lanes (bits 4 and 5 of the lane id)
            c += __shfl_xor(c, 16);
            c += __shfl_xor(c, 32);

            if (dosnap) {
                mx = fmaxf(mx, __shfl_xor(mx, 16));
                mx = fmaxf(mx, __shfl_xor(mx, 32));
                mn = fminf(mn, __shfl_xor(mn, 16));
                mn = fminf(mn, __shfl_xor(mn, 32));
                if      (c == mid + 1) { x = mx; active = false; }
                else if (c == mid)     { x = mn; active = false; }
                else {
                    if (c > mid + 1) hi = mx;   // snap to data: strict shrink
                    else             lo = mn;
                    if (lo >= hi) { x = lo; active = false; }
                    else {
                        float mN = m + ((float)(mid - c) + 0.5f) * invd;
                        if (!(mN > lo && mN < hi)) mN = 0.5f * (lo + hi);
                        if (mN >= hi) mN = lo;
                        m = mN;
                    }
                }
            } else {
                if (c == mid + 1 || c == mid) {
                    need_snap = true;           // redo same pivot with snap
                } else {
                    if (c > mid + 1) hi = m;    // answer in (lo, m]
                    else             lo = m;    // answer in (m, hi]
                    float mN = m + ((float)(mid - c) + 0.5f) * invd;
                    if (!(mN > lo && mN < hi)) mN = 0.5f * (lo + hi);
                    m = mN;
                }
            }
            ++pass;
        }
    }
    return x;
}

// ---------------------------------------------------------------------------
// Kernel 2: no LDS. Block = 256 thr = 4 independent waves; each wave owns 16
// columns of one node-half; each column is selected by 4 lanes.
// ---------------------------------------------------------------------------
__global__ __launch_bounds__(256, 4) void median_combine(
    const float* __restrict__ xT, const float* __restrict__ w,
    const int* __restrict__ nidx, const int* __restrict__ nlen,
    float* __restrict__ out)
{
    const int t   = threadIdx.x;
    const int wv  = t >> 6;            // wave 0..3
    const int l   = t & 63;
    const int g   = l & 15;            // column within wave's group
    const int q   = l >> 4;            // quarter 0..3
    const int n   = blockIdx.x >> 1;
    const int col = ((blockIdx.x & 1) << 6) | (wv << 4) | g;   // 0..127

    float medk[2];
    #pragma unroll
    for (int k = 0; k < 2; ++k) {
        const int ln = nlen[k * NN + n];                 // block-uniform
        const int* idxp = nidx + ((size_t)k * NN + n) * DMAX;
        medk[k] = (ln <= 32) ? median_sel<8>(xT, idxp, ln, col, q)
                             : median_sel<32>(xT, idxp, ln, col, q);
    }

    if (q == 0) {
        const float xv = xT[(size_t)n * ROWS + col];
        out[(size_t)col * NN + n] = w[0] * xv + w[1] * medk[0] + w[2] * medk[1];
    }
}

extern "C" void kernel_launch(void* const* d_in, const int* in_sizes, int n_in,
                              void* d_out, int out_size, void* d_ws, size_t ws_size,
                              hipStream_t stream) {
    const float* x    = (const float*)d_in[0];   // (2,64,10000) f32
    const float* w    = (const float*)d_in[1];   // (1,3) f32
    const int*   nidx = (const int*)d_in[2];     // (2,10000,128) i32
    const int*   nlen = (const int*)d_in[3];     // (2,10000) i32
    float* out = (float*)d_out;                  // (2,64,10000) f32
    float* xT  = (float*)d_ws;                   // 10000*128 f32 = 5.12 MB scratch

    dim3 tb(32, 8);
    dim3 tg((NN + 31) / 32, ROWS / 32);
    transpose_kernel<<<tg, tb, 0, stream>>>(x, xT);
    median_combine<<<NN * 2, 256, 0, stream>>>(xT, w, nidx, nlen, out);
}

// Round 5
// 356.583 us; speedup vs baseline: 1.3694x; 1.3694x over previous
//
#include <hip/hip_runtime.h>
#include <hip/hip_bf16.h>

// Problem constants (from reference)
constexpr int NN   = 10000;  // N_NODES
constexpr int DMAX = 128;    // D_MAX
constexpr int ROWS = 128;    // B*F = 2*64 values per node

// ---------------------------------------------------------------------------
// Kernel 1: transpose x (128, 10000) -> xT (10000, 128): each node's 128
// (b,f) values become one contiguous 512B line (coalesced neighbor gathers).
// ---------------------------------------------------------------------------
__global__ __launch_bounds__(256) void transpose_kernel(
    const float* __restrict__ x, float* __restrict__ xT)
{
    __shared__ float tile[32][33];
    const int n0 = blockIdx.x * 32;
    const int r0 = blockIdx.y * 32;
    const int tx = threadIdx.x;   // 0..31
    const int ty = threadIdx.y;   // 0..7
    #pragma unroll
    for (int i = 0; i < 32; i += 8) {
        const int r = r0 + ty + i;
        const int n = n0 + tx;
        if (n < NN) tile[ty + i][tx] = x[(size_t)r * NN + n];
    }
    __syncthreads();
    #pragma unroll
    for (int i = 0; i < 32; i += 8) {
        const int n = n0 + ty + i;
        const int r = r0 + tx;
        if (n < NN) xT[(size_t)n * ROWS + r] = tile[tx][ty + i];
    }
}

// ---------------------------------------------------------------------------
// Register-resident exact median, 2 lanes per column (half = lane>>5), each
// lane holds up to QC values in VGPRs (gathered once, 32-bit addressing).
// Bracketed quickselect, same proven termination logic as rounds 2-3:
//   pass: c = #{v<=m}; snap passes also track mx=max{v<=m}, mn=min{v>m}.
//   c==mid+1 -> x=mx ; c==mid -> x=mn ; lo>=hi -> x=lo  (duplicate-safe)
//   c>mid+1 -> hi=mx|m ; c<mid -> lo=mn|m  (bracket shrinks strictly)
// dosnap is WAVE-UNIFORM (ballot), so only one loop body issues per pass;
// pivot = secant on the empirical CDF with bracket clamps.
// The 2 lanes of a column carry identical scalar state -> lockstep exit.
// ---------------------------------------------------------------------------
template<int QC>
__device__ __forceinline__ float median_sel(const float* __restrict__ xT,
                                            const int* __restrict__ idxp,
                                            int ln, int col, int half)
{
    const float INF = 1e30f;
    float data[QC];
    #pragma unroll
    for (int j = 0; j < QC; ++j) {
        const int  jj    = half * QC + j;
        const bool valid = jj < ln;
        const int  nb    = valid ? idxp[jj] : 0;     // idxp has DMAX entries
        const float v    = xT[(nb << 7) + col];      // always in-bounds
        data[j] = valid ? v : INF;                   // pads never count
    }

    const int   mid  = (ln - 1) >> 1;
    const float midf = (float)mid + 0.5f;
    const float invs = 1.0f / (0.4f * (float)ln);    // Newton slope (N(0,1) pdf)
    float lo = -64.f, hi = 64.f, m = 0.f, x = 0.f;   // |data| < 10 << 64
    float mp = 0.f, cpf = 0.f;
    bool active = true, need_snap = false, have_prev = false;
    int  pass = 0;

    while (__ballot(active) != 0ull) {
        const bool dosnap = (pass >= 3) || (__ballot(need_snap) != 0ull); // uniform

        int   cA = 0, cB = 0, cC = 0, cD = 0;
        float mx0 = -INF, mx1 = -INF, mn0 = INF, mn1 = INF;
        if (dosnap) {
            #pragma unroll
            for (int j = 0; j < QC; j += 4) {
                const float v0 = data[j], v1 = data[j+1],
                            v2 = data[j+2], v3 = data[j+3];
                const bool l0 = v0 <= m, l1 = v1 <= m,
                           l2 = v2 <= m, l3 = v3 <= m;
                cA += l0; cB += l1; cC += l2; cD += l3;
                mx0 = l0 ? fmaxf(mx0, v0) : mx0;  mn0 = l0 ? mn0 : fminf(mn0, v0);
                mx1 = l1 ? fmaxf(mx1, v1) : mx1;  mn1 = l1 ? mn1 : fminf(mn1, v1);
                mx0 = l2 ? fmaxf(mx0, v2) : mx0;  mn0 = l2 ? mn0 : fminf(mn0, v2);
                mx1 = l3 ? fmaxf(mx1, v3) : mx1;  mn1 = l3 ? mn1 : fminf(mn1, v3);
            }
        } else {
            #pragma unroll
            for (int j = 0; j < QC; j += 4) {
                cA += data[j]   <= m;  cB += data[j+1] <= m;
                cC += data[j+2] <= m;  cD += data[j+3] <= m;
            }
        }
        int c = (cA + cB) + (cC + cD);
        c += __shfl_xor(c, 32);                      // combine the two halves
        float mx = fmaxf(mx0, mx1), mn = fminf(mn0, mn1);
        if (dosnap) {
            mx = fmaxf(mx, __shfl_xor(mx, 32));
            mn = fminf(mn, __shfl_xor(mn, 32));
        }

        if (active) {
            const float fc = (float)c;
            if (dosnap) {
                need_snap = false;
                if      (c == mid + 1) { x = mx; active = false; }
                else if (c == mid)     { x = mn; active = false; }
                else {
                    if (c > mid + 1) hi = mx; else lo = mn;     // snap: strict shrink
                    if (lo >= hi) { x = lo; active = false; }
                    else {
                        const float dd = fc - cpf;
                        float mN = (have_prev && dd != 0.f)
                                 ? m + (midf - fc) * (m - mp) * __builtin_amdgcn_rcpf(dd)
                                 : m + (midf - fc) * invs;
                        mp = m; cpf = fc; have_prev = true;
                        if (!(mN > lo && mN < hi)) mN = 0.5f * (lo + hi);
                        if (mN >= hi) mN = lo;                  // termination guard
                        m = mN;
                    }
                }
            } else {
                if (c == mid + 1 || c == mid) {
                    need_snap = true;                // redo same pivot with snap
                } else {
                    if (c > mid + 1) hi = m; else lo = m;
                    const float dd = fc - cpf;
                    float mN = (have_prev && dd != 0.f)
                             ? m + (midf - fc) * (m - mp) * __builtin_amdgcn_rcpf(dd)
                             : m + (midf - fc) * invs;
                    mp = m; cpf = fc; have_prev = true;
                    if (!(mN > lo && mN < hi)) mN = 0.5f * (lo + hi);
                    if (mN >= hi) mN = lo;
                    m = mN;
                }
            }
        }
        ++pass;
    }
    return x;
}

// ln is block-uniform -> this branch chain is uniform; only one path executes.
__device__ __forceinline__ float median_dispatch(const float* __restrict__ xT,
                                                 const int* __restrict__ idxp,
                                                 int ln, int col, int half)
{
    if (ln <= 16)  return median_sel< 8>(xT, idxp, ln, col, half);
    if (ln <= 32)  return median_sel<16>(xT, idxp, ln, col, half);
    if (ln <= 48)  return median_sel<24>(xT, idxp, ln, col, half);
    if (ln <= 64)  return median_sel<32>(xT, idxp, ln, col, half);
    if (ln <= 80)  return median_sel<40>(xT, idxp, ln, col, half);
    if (ln <= 96)  return median_sel<48>(xT, idxp, ln, col, half);
    if (ln <= 112) return median_sel<56>(xT, idxp, ln, col, half);
    return median_sel<64>(xT, idxp, ln, col, half);
}

// ---------------------------------------------------------------------------
// Kernel 2: no LDS, no __syncthreads. Block = 256 thr = 4 independent waves,
// one node per block; each wave owns 32 columns; each column = 2 lanes.
// ---------------------------------------------------------------------------
__global__ __launch_bounds__(256, 4) void median_combine(
    const float* __restrict__ xT, const float* __restrict__ w,
    const int* __restrict__ nidx, const int* __restrict__ nlen,
    float* __restrict__ out)
{
    const int t    = threadIdx.x;
    const int wv   = t >> 6;                 // wave 0..3
    const int l    = t & 63;
    const int col  = (wv << 5) | (l & 31);   // 0..127 (= b*64+f)
    const int half = l >> 5;                 // 0 or 1: which j-half I hold
    const int n    = blockIdx.x;

    float medk[2];
    #pragma unroll
    for (int k = 0; k < 2; ++k) {
        const int ln = nlen[k * NN + n];                     // block-uniform
        const int* idxp = nidx + ((size_t)k * NN + n) * DMAX;
        medk[k] = median_dispatch(xT, idxp, ln, col, half);
    }

    if (half == 0) {
        const float xv = xT[(n << 7) + col];
        out[col * NN + n] = w[0] * xv + w[1] * medk[0] + w[2] * medk[1];
    }
}

extern "C" void kernel_launch(void* const* d_in, const int* in_sizes, int n_in,
                              void* d_out, int out_size, void* d_ws, size_t ws_size,
                              hipStream_t stream) {
    const float* x    = (const float*)d_in[0];   // (2,64,10000) f32
    const float* w    = (const float*)d_in[1];   // (1,3) f32
    const int*   nidx = (const int*)d_in[2];     // (2,10000,128) i32
    const int*   nlen = (const int*)d_in[3];     // (2,10000) i32
    float* out = (float*)d_out;                  // (2,64,10000) f32
    float* xT  = (float*)d_ws;                   // 10000*128 f32 = 5.12 MB scratch

    dim3 tb(32, 8);
    dim3 tg((NN + 31) / 32, ROWS / 32);
    transpose_kernel<<<tg, tb, 0, stream>>>(x, xT);
    median_combine<<<NN, 256, 0, stream>>>(xT, w, nidx, nlen, out);
}